// Round 9
// baseline (563.848 us; speedup 1.0000x reference)
//
#include <hip/hip_runtime.h>
#include <hip/hip_bf16.h>
#include <stdint.h>

typedef __bf16 bf16;
typedef __attribute__((ext_vector_type(8))) __bf16 bf16x8;
typedef __attribute__((ext_vector_type(4))) float f32x4;

#define NNODE 20000
#define NEDGE 160000
#define NFEATD 512
#define NHIDD 256
#define NCLSD 64

// async global->LDS, 16B per lane (wave-uniform base + lane*16 contiguous)
__device__ __forceinline__ void async_copy16(const bf16* g, bf16* l) {
  __builtin_amdgcn_global_load_lds((__attribute__((address_space(1))) void*)g,
                                   (__attribute__((address_space(3))) void*)l,
                                   16, 0, 0);
}

// ---------------------------------------------------------------------------
// GEMM: Cint[M x Nint] = [A1|A2] @ [W1|W2]^T, fp32 accum.
// K-loop: R1 skeleton (best measured): BK=64, double-buffered LDS, depth-2
// prefetch, counted s_waitcnt vmcnt(8) (never drained mid-loop), two raw
// s_barriers per iter. XOR swizzle (phys 16B-slot = logical ^ (row&7)) on
// BOTH global_load_lds SOURCE and frag-read (involution) -> 0 bank
// conflicts. Bijective XCD-chunked block swizzle over the GEMM sub-grid.
// ROLE SPLIT (R9): blocks with orig >= nGemm run a gather role instead
// (early-return, no LDS/barrier use). GM=1: neighbor-mean (rowptr/adjr,
// nbscale, bf16 out). GM=2: GCN aggregation (colptr/adjc, dinv-weighted,
// fp32 out). GW = row width in elements.
// MODE 0: outB[r*ldC+c] = bf16(Cint)
// MODE 2: interleaved gamma/beta FiLM epilogue -> outG fp32 + outB2 bf16
// MODE 3: hk = (agg + dinv^2*hself + bias + C)*rnb, opt elu -> outB bf16
// MODE 4: MODE3 (no elu) + fused log_softmax over 64 cols -> outF, outF2
// ---------------------------------------------------------------------------
struct GemmArgs {
  const bf16 *A1, *A2, *W1, *W2, *zpage;
  int ldA, ldW, K1, Ktot, Nvalid, ldC, Nrows, Arows, Wrows;
  int gxG, nGemm;      // GEMM sub-grid: width in tiles, total GEMM blocks
  bf16* outB;
  float* outF;
  float* outF2;
  const float* mrow;   // MODE 2
  const float* Xf;     // MODE 2 layer1 ft fp32 (or null)
  const bf16* Xh;      // MODE 2 layer2 ft bf16
  const bf16* nbm;     // MODE 2
  float* outG;         // MODE 2 fp32 into d_out
  bf16* outB2;         // MODE 2 bf16 copy
  const float* agg;    // MODE 3/4
  const bf16* hself;
  int hld;
  const float* dinv;
  const float* bias;
  const float* rnb;
  int elu;
  // gather role (GM != 0)
  const int* gptr;
  const int* gadj;
  const bf16* gsrc;
  bf16* gdstB;         // GM=1 output
  float* gdstF;        // GM=2 output
  const float* gnbs;   // GM=1 scale
};

template <int MODE, int GM, int GW>
__global__ __launch_bounds__(256) void gemm_bt(GemmArgs ga) {
  __shared__ bf16 sA[2][128 * 64];
  __shared__ bf16 sB[2][128 * 64];
  const int tid = threadIdx.x;
  const int orig = blockIdx.x;

  // ================= gather role (early return, no LDS/barriers) ==========
  if constexpr (GM == 1) {
    if (orig >= ga.nGemm) {
      const int r = (orig - ga.nGemm) * 4 + (tid >> 6);
      if (r < NNODE) {
        const int lane = tid & 63;
        const int e0 = ga.gptr[r], e1 = ga.gptr[r + 1];
        if constexpr (GW == 512) {
          float a[8] = {};
          int e = e0;
          for (; e + 8 <= e1; e += 8) {
            union { uint4 u; bf16 b[8]; } v[8];
            int ix[8];
#pragma unroll
            for (int k = 0; k < 8; k++) ix[k] = ga.gadj[e + k];
#pragma unroll
            for (int k = 0; k < 8; k++)
              v[k].u = *(const uint4*)(ga.gsrc + (size_t)ix[k] * 512 + lane * 8);
#pragma unroll
            for (int j = 0; j < 8; j++) {
              float t = 0.f;
#pragma unroll
              for (int k = 0; k < 8; k++) t += (float)v[k].b[j];
              a[j] += t;
            }
          }
          for (; e < e1; e++) {
            union { uint4 u; bf16 b[8]; } v;
            v.u = *(const uint4*)(ga.gsrc + (size_t)ga.gadj[e] * 512 + lane * 8);
#pragma unroll
            for (int j = 0; j < 8; j++) a[j] += (float)v.b[j];
          }
          float s = ga.gnbs[r];
          union { bf16 b[8]; uint4 u; } o;
#pragma unroll
          for (int j = 0; j < 8; j++) o.b[j] = (bf16)(a[j] * s);
          *(uint4*)(ga.gdstB + (size_t)r * 512 + lane * 8) = o.u;
        } else {  // GW == 256
          float a[4] = {};
          int e = e0;
          for (; e + 8 <= e1; e += 8) {
            union { uint2 u; bf16 b[4]; } v[8];
            int ix[8];
#pragma unroll
            for (int k = 0; k < 8; k++) ix[k] = ga.gadj[e + k];
#pragma unroll
            for (int k = 0; k < 8; k++)
              v[k].u = *(const uint2*)(ga.gsrc + (size_t)ix[k] * 256 + lane * 4);
#pragma unroll
            for (int j = 0; j < 4; j++) {
              float t = 0.f;
#pragma unroll
              for (int k = 0; k < 8; k++) t += (float)v[k].b[j];
              a[j] += t;
            }
          }
          for (; e < e1; e++) {
            union { uint2 u; bf16 b[4]; } v;
            v.u = *(const uint2*)(ga.gsrc + (size_t)ga.gadj[e] * 256 + lane * 4);
#pragma unroll
            for (int j = 0; j < 4; j++) a[j] += (float)v.b[j];
          }
          float s = ga.gnbs[r];
          union { bf16 b[4]; uint2 u; } o;
#pragma unroll
          for (int j = 0; j < 4; j++) o.b[j] = (bf16)(a[j] * s);
          *(uint2*)(ga.gdstB + (size_t)r * 256 + lane * 4) = o.u;
        }
      }
      return;
    }
  } else if constexpr (GM == 2) {
    if (orig >= ga.nGemm) {
      const int r = (orig - ga.nGemm) * 4 + (tid >> 6);
      if (r < NNODE) {
        const int lane = tid & 63;
        const int e0 = ga.gptr[r], e1 = ga.gptr[r + 1];
        if constexpr (GW == 256) {
          float a[4] = {};
          int e = e0;
          for (; e + 8 <= e1; e += 8) {
            union { uint2 u; bf16 b[4]; } v[8];
            int ix[8];
            float wv[8];
#pragma unroll
            for (int k = 0; k < 8; k++) ix[k] = ga.gadj[e + k];
#pragma unroll
            for (int k = 0; k < 8; k++) wv[k] = ga.dinv[ix[k]];
#pragma unroll
            for (int k = 0; k < 8; k++)
              v[k].u = *(const uint2*)(ga.gsrc + (size_t)ix[k] * 256 + lane * 4);
#pragma unroll
            for (int j = 0; j < 4; j++) {
              float t = 0.f;
#pragma unroll
              for (int k = 0; k < 8; k++) t += wv[k] * (float)v[k].b[j];
              a[j] += t;
            }
          }
          for (; e < e1; e++) {
            int i0 = ga.gadj[e];
            float w0 = ga.dinv[i0];
            union { uint2 u; bf16 b[4]; } v;
            v.u = *(const uint2*)(ga.gsrc + (size_t)i0 * 256 + lane * 4);
#pragma unroll
            for (int j = 0; j < 4; j++) a[j] += w0 * (float)v.b[j];
          }
          float wc = ga.dinv[r];
          f32x4 o;
#pragma unroll
          for (int j = 0; j < 4; j++) o[j] = a[j] * wc;
          *(f32x4*)(ga.gdstF + (size_t)r * 256 + lane * 4) = o;
        } else {  // GW == 64
          float a = 0.f;
          int e = e0;
          for (; e + 4 <= e1; e += 4) {
            int i0 = ga.gadj[e], i1 = ga.gadj[e + 1], i2 = ga.gadj[e + 2], i3 = ga.gadj[e + 3];
            float h0 = (float)ga.gsrc[(size_t)i0 * 64 + lane];
            float h1 = (float)ga.gsrc[(size_t)i1 * 64 + lane];
            float h2 = (float)ga.gsrc[(size_t)i2 * 64 + lane];
            float h3 = (float)ga.gsrc[(size_t)i3 * 64 + lane];
            a += ga.dinv[i0] * h0 + ga.dinv[i1] * h1 + ga.dinv[i2] * h2 + ga.dinv[i3] * h3;
          }
          for (; e < e1; e++) {
            int rr = ga.gadj[e];
            a += ga.dinv[rr] * (float)ga.gsrc[(size_t)rr * 64 + lane];
          }
          ga.gdstF[(size_t)r * 64 + lane] = a * ga.dinv[r];
        }
      }
      return;
    }
  }

  // ================= GEMM role ============================================
  const int lane = tid & 63;
  const int w = tid >> 6;
  const int wm = w >> 1, wn = w & 1;

  // --- bijective XCD-chunked block swizzle (m204) over the GEMM sub-grid.
  const int gx = ga.gxG;
  const int nwg = ga.nGemm;
  const int qq = nwg >> 3, rm = nwg & 7;
  const int xcd = orig & 7, sidx = orig >> 3;
  const int wg = (xcd < rm ? xcd * (qq + 1) : rm * (qq + 1) + (xcd - rm) * qq) + sidx;
  const int bn0 = (wg % gx) * 128;
  const int bm0 = (wg / gx) * 128;

  // --- staging precompute (swizzle: phys 16B-slot = logical ^ (row&7)).
  const int srow = tid >> 3;
  const int scol = (((tid & 7) ^ (srow & 7)) << 3);  // element offset within row
  const bf16* zp = ga.zpage + tid * 8;
  int offA[4], offB[4];
  bool okA[4], okB[4];
#pragma unroll
  for (int r = 0; r < 4; r++) {
    const int ra = bm0 + r * 32 + srow;
    const int rb = bn0 + r * 32 + srow;
    okA[r] = ra < ga.Arows;
    okB[r] = rb < ga.Wrows;
    offA[r] = ra * ga.ldA + scol;
    offB[r] = rb * ga.ldW + scol;
  }
  const int nt1 = ga.K1 >> 6;
  const int nt = ga.Ktot >> 6;

  auto stage = [&](int t, int p) {
    const int seg = t >= nt1;
    const int koff = (t - (seg ? nt1 : 0)) << 6;
    const bf16* As = seg ? ga.A2 : ga.A1;
    const bf16* Ws = seg ? ga.W2 : ga.W1;
    bf16* dA = &sA[p][tid * 8];
    bf16* dB = &sB[p][tid * 8];
#pragma unroll
    for (int r = 0; r < 4; r++)
      async_copy16(okA[r] ? As + offA[r] + koff : zp, dA + r * 2048);
#pragma unroll
    for (int r = 0; r < 4; r++)
      async_copy16(okB[r] ? Ws + offB[r] + koff : zp, dB + r * 2048);
  };

  // --- fragment-read precompute.
  const int sl = lane >> 4;
  const int rAb = wm * 64 + (lane & 15);
  const int rBb = wn * 64 + (lane & 15);
  const int a7 = rAb & 7, b7 = rBb & 7;

  f32x4 acc[4][4] = {};

  // --- prologue: stage tiles 0,1; wait tile0 (8 of tile1 stay in flight).
  stage(0, 0);
  stage(1, 1);
  asm volatile("s_waitcnt vmcnt(8)" ::: "memory");
  __builtin_amdgcn_s_barrier();
  asm volatile("" ::: "memory");

  for (int t = 0; t < nt; ++t) {
    const int p = t & 1;
    const bf16* pA = &sA[p][0];
    const bf16* pB = &sB[p][0];
    bf16x8 af[4][2], bv[4][2];
#pragma unroll
    for (int mi = 0; mi < 4; mi++)
#pragma unroll
      for (int kk = 0; kk < 2; kk++)
        af[mi][kk] = *(const bf16x8*)((const char*)pA + (rAb + mi * 16) * 128 +
                                      ((((kk << 2) + sl) ^ a7) << 4));
#pragma unroll
    for (int ni = 0; ni < 4; ni++)
#pragma unroll
      for (int kk = 0; kk < 2; kk++)
        bv[ni][kk] = *(const bf16x8*)((const char*)pB + (rBb + ni * 16) * 128 +
                                      ((((kk << 2) + sl) ^ b7) << 4));
    if (t + 2 < nt) {
      asm volatile("s_waitcnt lgkmcnt(0)" ::: "memory");
      __builtin_amdgcn_s_barrier();
      asm volatile("" ::: "memory");
      stage(t + 2, p);  // issue early: HBM latency hides under MFMA below
    }
    __builtin_amdgcn_s_setprio(1);
#pragma unroll
    for (int mi = 0; mi < 4; mi++)
#pragma unroll
      for (int ni = 0; ni < 4; ni++)
#pragma unroll
        for (int kk = 0; kk < 2; kk++)
          acc[mi][ni] =
              __builtin_amdgcn_mfma_f32_16x16x32_bf16(af[mi][kk], bv[ni][kk], acc[mi][ni], 0, 0, 0);
    __builtin_amdgcn_s_setprio(0);
    if (t + 1 < nt) {
      if (t + 2 < nt) asm volatile("s_waitcnt vmcnt(8)" ::: "memory");
      else            asm volatile("s_waitcnt vmcnt(0)" ::: "memory");
      __builtin_amdgcn_s_barrier();
      asm volatile("" ::: "memory");
    }
  }

  if constexpr (MODE == 0) {
    const int Nv = ga.Nvalid;
#pragma unroll
    for (int mi = 0; mi < 4; mi++) {
      const int rb = bm0 + wm * 64 + mi * 16 + ((lane >> 4) << 2);
#pragma unroll
      for (int ni = 0; ni < 4; ni++) {
        const int c = bn0 + wn * 64 + ni * 16 + (lane & 15);
#pragma unroll
        for (int i = 0; i < 4; i++) {
          const int r = rb + i;
          if (r < ga.Nrows && c < Nv) ga.outB[(size_t)r * ga.ldC + c] = (bf16)acc[mi][ni][i];
        }
      }
    }
  } else if constexpr (MODE == 2) {
    const int Dr = ga.Nvalid;  // logical width
    const int Lb = ((bn0 + wn * 64) >> 1) + (lane & 15);
#pragma unroll
    for (int mi = 0; mi < 4; mi++) {
      const int rb = bm0 + wm * 64 + mi * 16 + ((lane >> 4) << 2);
#pragma unroll
      for (int p = 0; p < 2; p++) {
        const int L = Lb + p * 16;
        const float mv = ga.mrow[L];
#pragma unroll
        for (int i = 0; i < 4; i++) {
          const int r = rb + i;
          if (r >= ga.Nrows) continue;
          const size_t idx = (size_t)r * Dr + L;
          float vg = acc[mi][2 * p][i];
          float vb = acc[mi][2 * p + 1][i];
          float gamma = (vg > 0.f ? vg : 0.2f * vg) + 1.0f;
          float beta = vb > 0.f ? vb : 0.2f * vb;
          float ft = ga.Xf ? ga.Xf[idx] : (float)ga.Xh[idx];
          float o = ft + gamma * mv + beta - (float)ga.nbm[idx];
          ga.outG[idx] = o;
          ga.outB2[idx] = (bf16)o;
        }
      }
    }
  } else if constexpr (MODE == 3) {
    const int Nv = ga.Nvalid;
#pragma unroll
    for (int mi = 0; mi < 4; mi++) {
      const int rb = bm0 + wm * 64 + mi * 16 + ((lane >> 4) << 2);
#pragma unroll
      for (int ni = 0; ni < 4; ni++) {
        const int c = bn0 + wn * 64 + ni * 16 + (lane & 15);
#pragma unroll
        for (int i = 0; i < 4; i++) {
          const int r = rb + i;
          if (r >= ga.Nrows || c >= Nv) continue;
          const size_t idx = (size_t)r * ga.ldC + c;
          float dv = ga.dinv[r];
          float hs = (float)ga.hself[(size_t)r * ga.hld + c];
          float hv = (ga.agg[idx] + dv * dv * hs + ga.bias[c] + acc[mi][ni][i]) * ga.rnb[r];
          if (ga.elu) hv = hv > 0.f ? hv : expm1f(hv);
          ga.outB[idx] = (bf16)hv;
        }
      }
    }
  } else {  // MODE 4: GCN combine + fused log_softmax (Nvalid == 64, wn==0 waves only)
    if (wn == 0) {
#pragma unroll
      for (int mi = 0; mi < 4; mi++) {
        const int rb = bm0 + wm * 64 + mi * 16 + ((lane >> 4) << 2);
#pragma unroll
        for (int i = 0; i < 4; i++) {
          const int r = rb + i;
          const bool ok = r < ga.Nrows;  // uniform within the 16-lane shuffle group
          float dv = ok ? ga.dinv[r] : 0.f;
          float rn = ok ? ga.rnb[r] : 1.f;
          float hv[4];
#pragma unroll
          for (int ni = 0; ni < 4; ni++) {
            const int c = ni * 16 + (lane & 15);
            float hs = ok ? (float)ga.hself[(size_t)r * ga.hld + c] : 0.f;
            float ag = ok ? ga.agg[(size_t)r * 64 + c] : 0.f;
            hv[ni] = ok ? (ag + dv * dv * hs + ga.bias[c] + acc[mi][ni][i]) * rn : 0.f;
          }
          float mx = fmaxf(fmaxf(hv[0], hv[1]), fmaxf(hv[2], hv[3]));
          mx = fmaxf(mx, __shfl_xor(mx, 1));
          mx = fmaxf(mx, __shfl_xor(mx, 2));
          mx = fmaxf(mx, __shfl_xor(mx, 4));
          mx = fmaxf(mx, __shfl_xor(mx, 8));
          float s = expf(hv[0] - mx) + expf(hv[1] - mx) + expf(hv[2] - mx) + expf(hv[3] - mx);
          s += __shfl_xor(s, 1);
          s += __shfl_xor(s, 2);
          s += __shfl_xor(s, 4);
          s += __shfl_xor(s, 8);
          float ls = logf(s);
          if (ok) {
#pragma unroll
            for (int ni = 0; ni < 4; ni++) {
              const int c = ni * 16 + (lane & 15);
              ga.outF[(size_t)r * 64 + c] = hv[ni];
              ga.outF2[(size_t)r * 64 + c] = hv[ni] - mx - ls;
            }
          }
        }
      }
    }
  }
}

// ---------------------------------------------------------------------------
// prep_all: one dispatch replacing cvt_f2b x3, build_rel_w x2, and the three
// memsets (icr/icc/zpage). Region-dispatched by blockIdx.
// ---------------------------------------------------------------------------
#define PREP_NB0 10000
#define PREP_NB1 10128
#define PREP_NB2 10144
#define PREP_NB3 11168
#define PREP_NB4 11424
#define PREP_NB5 11589

__device__ __forceinline__ void cvt4(const float* __restrict__ src, bf16* __restrict__ dst,
                                     int i) {
  float4 v = *(const float4*)(src + i);
  union { bf16 b[4]; uint2 u; } o;
  o.b[0] = (bf16)v.x; o.b[1] = (bf16)v.y; o.b[2] = (bf16)v.z; o.b[3] = (bf16)v.w;
  *(uint2*)(dst + i) = o.u;
}

__device__ __forceinline__ void relw4(const float* __restrict__ g1, const float* __restrict__ g2,
                                      const float* __restrict__ b1, const float* __restrict__ b2,
                                      bf16* __restrict__ dst, int D, int idx) {
  int R = idx / (2 * D), C = idx % (2 * D);
  int q = R >> 5, s = R & 31;
  int sr = q * 16 + (s & 15);
  const float* src = (s < 16) ? ((C < D) ? g1 : g2) : ((C < D) ? b1 : b2);
  int cc = (C < D) ? C : C - D;
  float4 v = *(const float4*)(src + (size_t)sr * D + cc);
  union { bf16 b[4]; uint2 u; } o;
  o.b[0] = (bf16)v.x; o.b[1] = (bf16)v.y; o.b[2] = (bf16)v.z; o.b[3] = (bf16)v.w;
  *(uint2*)(dst + (size_t)R * 2 * D + C) = o.u;
}

__global__ __launch_bounds__(256) void prep_all(
    const float* __restrict__ x, const float* __restrict__ gc1w, const float* __restrict__ gc2w,
    const float* __restrict__ r1g1, const float* __restrict__ r1g2,
    const float* __restrict__ r1b1, const float* __restrict__ r1b2,
    const float* __restrict__ r2g1, const float* __restrict__ r2g2,
    const float* __restrict__ r2b1, const float* __restrict__ r2b2,
    bf16* __restrict__ xb, bf16* __restrict__ wgc1, bf16* __restrict__ wgc2,
    bf16* __restrict__ Wrel1, bf16* __restrict__ Wrel2,
    int* __restrict__ icr, int* __restrict__ icc, int* __restrict__ zpage) {
  const int b = blockIdx.x;
  const int tid = threadIdx.x;
  if (b < PREP_NB0) {
    cvt4(x, xb, (b * 256 + tid) * 4);
  } else if (b < PREP_NB1) {
    cvt4(gc1w, wgc1, ((b - PREP_NB0) * 256 + tid) * 4);
  } else if (b < PREP_NB2) {
    cvt4(gc2w, wgc2, ((b - PREP_NB1) * 256 + tid) * 4);
  } else if (b < PREP_NB3) {
    relw4(r1g1, r1g2, r1b1, r1b2, Wrel1, 512, ((b - PREP_NB2) * 256 + tid) * 4);
  } else if (b < PREP_NB4) {
    relw4(r2g1, r2g2, r2b1, r2b2, Wrel2, 256, ((b - PREP_NB3) * 256 + tid) * 4);
  } else {
    int i = (b - PREP_NB4) * 256 + tid;
    if (i < NNODE) icr[i] = 0;
    else if (i < 2 * NNODE) icc[i - NNODE] = 0;
    else if (i < 2 * NNODE + 2048) zpage[i - 2 * NNODE] = 0;
  }
}

// ---------------------------------------------------------------------------
// CSR build
// ---------------------------------------------------------------------------
__global__ void count_int(const int* __restrict__ ei, int* cr, int* cc, int E) {
  int e = blockIdx.x * 256 + threadIdx.x;
  if (e < E) {
    atomicAdd(&cr[ei[e]], 1);
    atomicAdd(&cc[ei[E + e]], 1);
  }
}

// scan + folded finalize (nbscale/rnb/dinv from the completed counts)
__global__ void scan_excl2(const int* __restrict__ cr, const int* __restrict__ cc,
                           int* __restrict__ rptr, int* __restrict__ cptr,
                           int* __restrict__ curr, int* __restrict__ curc,
                           float* __restrict__ nbscale, float* __restrict__ rnb,
                           float* __restrict__ dinv, int n) {
  int t = threadIdx.x;
  {
    int b0 = blockIdx.x * (n / 2);
    for (int j = b0 + t; j < b0 + n / 2; j += 256) {
      float a = (float)cr[j];
      nbscale[j] = 1.0f / fmaxf(a, 1.0f);
      rnb[j] = 1.0f / (a + 1.0f);
      dinv[j] = rsqrtf((float)cc[j] + 1.0f);
    }
  }
  const int* cnt = blockIdx.x ? cc : cr;
  int* ptr = blockIdx.x ? cptr : rptr;
  int* cur = blockIdx.x ? curc : curr;
  __shared__ int part[256];
  int chunk = (n + 255) / 256;
  int base = t * chunk;
  int s = 0;
  for (int i = 0; i < chunk; i++) {
    int j = base + i;
    if (j < n) s += cnt[j];
  }
  part[t] = s;
  __syncthreads();
  if (t == 0) {
    int r = 0;
    for (int i = 0; i < 256; i++) { int v = part[i]; part[i] = r; r += v; }
    ptr[n] = r;
  }
  __syncthreads();
  int run = part[t];
  for (int i = 0; i < chunk; i++) {
    int j = base + i;
    if (j < n) {
      ptr[j] = run;
      cur[j] = run;
      run += cnt[j];
    }
  }
}

__global__ void csr_fill(const int* __restrict__ ei, int* cur_r, int* cur_c,
                         int* __restrict__ adj_r, int* __restrict__ adj_c, int E) {
  int e = blockIdx.x * 256 + threadIdx.x;
  if (e >= E) return;
  int row = ei[e], col = ei[E + e];
  int p = atomicAdd(&cur_r[row], 1);
  adj_r[p] = col;
  int q = atomicAdd(&cur_c[col], 1);
  adj_c[q] = row;
}

// ---------------------------------------------------------------------------
extern "C" void kernel_launch(void* const* d_in, const int* in_sizes, int n_in, void* d_out,
                              int out_size, void* d_ws, size_t ws_size, hipStream_t stream) {
  const float* x = (const float*)d_in[0];
  const int* ei = (const int*)d_in[1];
  // d_in[2] = head (always 0 -> tail branch)
  const float* r1g1 = (const float*)d_in[3];
  const float* r1g2 = (const float*)d_in[4];
  const float* r1b1 = (const float*)d_in[5];
  const float* r1b2 = (const float*)d_in[6];
  const float* r1m = (const float*)d_in[7];
  const float* gc1w = (const float*)d_in[8];
  const float* gc1b = (const float*)d_in[9];
  const float* r2g1 = (const float*)d_in[10];
  const float* r2g2 = (const float*)d_in[11];
  const float* r2b1 = (const float*)d_in[12];
  const float* r2b2 = (const float*)d_in[13];
  const float* r2m = (const float*)d_in[14];
  const float* gc2w = (const float*)d_in[15];
  const float* gc2b = (const float*)d_in[16];
  float* out = (float*)d_out;

  char* ws = (char*)d_ws;
  size_t off = 0;
  auto alloc = [&](size_t bytes) -> char* {
    char* p = ws + off;
    off = (off + bytes + 511) & ~(size_t)511;
    return p;
  };
  float* nbscale = (float*)alloc((size_t)NNODE * 4);
  float* rnb = (float*)alloc((size_t)NNODE * 4);
  float* dinv = (float*)alloc((size_t)NNODE * 4);
  int* icr = (int*)alloc((size_t)NNODE * 4);
  int* icc = (int*)alloc((size_t)NNODE * 4);
  int* rptr = (int*)alloc((size_t)(NNODE + 1) * 4);
  int* cptr = (int*)alloc((size_t)(NNODE + 1) * 4);
  int* curr = (int*)alloc((size_t)NNODE * 4);
  int* curc = (int*)alloc((size_t)NNODE * 4);
  int* adjr = (int*)alloc((size_t)NEDGE * 4);
  int* adjc = (int*)alloc((size_t)NEDGE * 4);
  bf16* zpage = (bf16*)alloc(8192);
  bf16* Wrel1 = (bf16*)alloc((size_t)1024 * 1024 * 2);  // interleaved [g;b] layer1
  bf16* Wrel2 = (bf16*)alloc((size_t)512 * 512 * 2);    // interleaved [g;b] layer2
  bf16* wgc1 = (bf16*)alloc((size_t)NHIDD * NFEATD * 2);
  bf16* wgc2 = (bf16*)alloc((size_t)NCLSD * NHIDD * 2);
  bf16* xb = (bf16*)alloc((size_t)NNODE * NFEATD * 2);     // 20.5 MB
  bf16* nbp1 = (bf16*)alloc((size_t)NNODE * NFEATD * 2);   // 20.5 MB
  bf16* out1b = (bf16*)alloc((size_t)NNODE * NFEATD * 2);  // 20.5 MB
  bf16* h1b = (bf16*)alloc((size_t)NNODE * NHIDD * 2);     // 10.2 MB
  float* agg1 = (float*)alloc((size_t)NNODE * NHIDD * 4);  // 20.5 MB
  bf16* x1b = (bf16*)alloc((size_t)NNODE * NHIDD * 2);     // 10.2 MB
  bf16* nb2p = (bf16*)alloc((size_t)NNODE * NHIDD * 2);    // 10.2 MB
  bf16* out2b = (bf16*)alloc((size_t)NNODE * NHIDD * 2);   // 10.2 MB
  bf16* h2b = (bf16*)alloc((size_t)NNODE * NCLSD * 2);     // 2.6 MB
  float* agg2 = (float*)alloc((size_t)NNODE * NCLSD * 4);  // 5.1 MB

  const size_t OUT1OFF = (size_t)2 * NNODE * NCLSD;
  const size_t OUT2OFF = OUT1OFF + (size_t)NNODE * NFEATD;
  float* out1g = out + OUT1OFF;
  float* out2g = out + OUT2OFF;

  const int MB = (NNODE + 127) / 128;  // 157
  const int NW4 = (NNODE + 3) / 4;     // 5000

  // ---- fused prep: conversions + weight builders + counter/zpage zeroing ----
  prep_all<<<PREP_NB5, 256, 0, stream>>>(x, gc1w, gc2w, r1g1, r1g2, r1b1, r1b2,
                                         r2g1, r2g2, r2b1, r2b2, xb, wgc1, wgc2,
                                         Wrel1, Wrel2, icr, icc, (int*)zpage);

  // ---- CSR build + graph stats ----
  count_int<<<(NEDGE + 255) / 256, 256, 0, stream>>>(ei, icr, icc, NEDGE);
  scan_excl2<<<2, 256, 0, stream>>>(icr, icc, rptr, cptr, curr, curc, nbscale, rnb, dinv, NNODE);
  csr_fill<<<(NEDGE + 255) / 256, 256, 0, stream>>>(ei, curr, curc, adjr, adjc, NEDGE);

  GemmArgs a;
  auto base = [&](const bf16* A1, const bf16* A2, int ldA, const bf16* W1, const bf16* W2,
                  int ldW, int K1, int Kt, int Nv, int ldC, int Wr) {
    a = GemmArgs{};
    a.A1 = A1; a.A2 = A2; a.W1 = W1; a.W2 = W2; a.zpage = zpage;
    a.ldA = ldA; a.ldW = ldW; a.K1 = K1; a.Ktot = Kt; a.Nvalid = Nv; a.ldC = ldC;
    a.Nrows = NNODE; a.Arows = NNODE; a.Wrows = Wr;
  };

  // ---- D1: h1 = bf16(xb @ gc1^T)  +  nb1 neighbor-mean gather ----
  base(xb, xb, NFEATD, wgc1, wgc1, NFEATD, NFEATD, NFEATD, NHIDD, NHIDD, NHIDD);
  a.outB = h1b; a.gxG = 2; a.nGemm = 2 * MB;
  a.gptr = rptr; a.gadj = adjr; a.gsrc = xb; a.gdstB = nbp1; a.gnbs = nbscale;
  gemm_bt<0, 1, 512><<<2 * MB + NW4, 256, 0, stream>>>(a);

  // ---- D2: relation-L1 (interleaved gamma/beta) + gcn256 gather (h1b->agg1) ----
  base(xb, nbp1, NFEATD, Wrel1, Wrel1 + 512, 1024, NFEATD, 2 * NFEATD, NFEATD, NFEATD, 1024);
  a.mrow = r1m; a.Xf = x; a.nbm = nbp1; a.outG = out1g; a.outB2 = out1b;
  a.gxG = 8; a.nGemm = 8 * MB;
  a.gptr = cptr; a.gadj = adjc; a.gsrc = h1b; a.gdstF = agg1; a.dinv = dinv;
  gemm_bt<2, 2, 256><<<8 * MB + NW4, 256, 0, stream>>>(a);

  // ---- D3: x1 = elu((agg1 + dinv^2*h1 + b1 + out1@gc1^T)*rnb) ----
  base(out1b, out1b, NFEATD, wgc1, wgc1, NFEATD, NFEATD, NFEATD, NHIDD, NHIDD, NHIDD);
  a.agg = agg1; a.hself = h1b; a.hld = NHIDD; a.dinv = dinv; a.bias = gc1b; a.rnb = rnb;
  a.elu = 1; a.outB = x1b; a.gxG = 2; a.nGemm = 2 * MB;
  gemm_bt<3, 0, 0><<<2 * MB, 256, 0, stream>>>(a);

  // ---- D4: h2 = bf16(x1 @ gc2^T)  +  nb2 neighbor-mean gather ----
  base(x1b, x1b, NHIDD, wgc2, wgc2, NHIDD, NHIDD, NHIDD, NCLSD, NCLSD, NCLSD);
  a.outB = h2b; a.gxG = 1; a.nGemm = MB;
  a.gptr = rptr; a.gadj = adjr; a.gsrc = x1b; a.gdstB = nb2p; a.gnbs = nbscale;
  gemm_bt<0, 1, 256><<<MB + NW4, 256, 0, stream>>>(a);

  // ---- D5: relation-L2 + gcn64 gather (h2b->agg2) ----
  base(x1b, nb2p, NHIDD, Wrel2, Wrel2 + 256, 512, NHIDD, 2 * NHIDD, NHIDD, NHIDD, 512);
  a.mrow = r2m; a.Xf = nullptr; a.Xh = x1b; a.nbm = nb2p; a.outG = out2g; a.outB2 = out2b;
  a.gxG = 4; a.nGemm = 4 * MB;
  a.gptr = cptr; a.gadj = adjc; a.gsrc = h2b; a.gdstF = agg2; a.dinv = dinv;
  gemm_bt<2, 2, 64><<<4 * MB + NW4, 256, 0, stream>>>(a);

  // ---- D6: x2 + log_softmax fused ----
  base(out2b, out2b, NHIDD, wgc2, wgc2, NHIDD, NHIDD, NHIDD, NCLSD, NCLSD, NCLSD);
  a.agg = agg2; a.hself = h2b; a.hld = NCLSD; a.dinv = dinv; a.bias = gc2b; a.rnb = rnb;
  a.elu = 0; a.outF = out; a.outF2 = out + (size_t)NNODE * NCLSD;
  a.gxG = 1; a.nGemm = MB;
  gemm_bt<4, 0, 0><<<MB, 256, 0, stream>>>(a);
}

// Round 10
// 493.524 us; speedup vs baseline: 1.1425x; 1.1425x over previous
//
#include <hip/hip_runtime.h>
#include <hip/hip_bf16.h>
#include <stdint.h>

typedef __bf16 bf16;
typedef __attribute__((ext_vector_type(8))) __bf16 bf16x8;
typedef __attribute__((ext_vector_type(4))) float f32x4;

#define NNODE 20000
#define NEDGE 160000
#define NFEATD 512
#define NHIDD 256
#define NCLSD 64

// async global->LDS, 16B per lane (wave-uniform base + lane*16 contiguous)
__device__ __forceinline__ void async_copy16(const bf16* g, bf16* l) {
  __builtin_amdgcn_global_load_lds((__attribute__((address_space(1))) void*)g,
                                   (__attribute__((address_space(3))) void*)l,
                                   16, 0, 0);
}

// ---------------------------------------------------------------------------
// GEMM: Cint[M x Nint] = [A1|A2] @ [W1|W2]^T, fp32 accum.
// K-loop: R1 skeleton (best measured over R2/R3/R4 variants): BK=64,
// double-buffered LDS, depth-2 prefetch, counted s_waitcnt vmcnt(8) (never
// drained mid-loop), two raw s_barriers per iter. XOR swizzle (phys 16B-slot
// = logical ^ (row&7)) on BOTH global_load_lds SOURCE and frag-read
// (involution) -> 0 bank conflicts. Bijective XCD-chunked block swizzle.
// MODE 0: outB[r*ldC+c] = bf16(Cint)
// MODE 2: interleaved gamma/beta FiLM epilogue -> outG fp32 + outB2 bf16.
//         FUSION: blocks with bn0 >= Nintmain compute A1 @ Wh^T instead.
// MODE 3: hk = (agg + dinv^2*hself + bias + C)*rnb, opt elu -> outB bf16
// MODE 4: MODE3 (no elu) + fused log_softmax over 64 cols -> outF, outF2
// ---------------------------------------------------------------------------
struct GemmArgs {
  const bf16 *A1, *A2, *W1, *W2, *zpage;
  int ldA, ldW, K1, Ktot, Nvalid, ldC, Nrows, Arows, Wrows;
  bf16* outB;
  float* outF;
  float* outF2;
  const float* mrow;   // MODE 2
  const float* Xf;     // MODE 2 layer1 ft fp32 (or null)
  const bf16* Xh;      // MODE 2 layer2 ft bf16
  const bf16* nbm;     // MODE 2
  float* outG;         // MODE 2 fp32 into d_out
  bf16* outB2;         // MODE 2 bf16 copy
  const float* agg;    // MODE 3/4
  const bf16* hself;
  int hld;
  const float* dinv;
  const float* bias;
  const float* rnb;
  int elu;
  // fused secondary GEMM (MODE 2 only)
  const bf16* Wh;      // secondary weights (row-major [Wrowsh x ldWh])
  int ldWh, Wrowsh, Kh, Nintmain;
};

template <int MODE>
__global__ __launch_bounds__(256) void gemm_bt(GemmArgs ga) {
  __shared__ bf16 sA[2][128 * 64];
  __shared__ bf16 sB[2][128 * 64];
  const int tid = threadIdx.x;
  const int lane = tid & 63;
  const int w = tid >> 6;
  const int wm = w >> 1, wn = w & 1;

  // --- bijective XCD-chunked block swizzle (m204).
  const int gx = gridDim.x;
  const int nwg = gx * gridDim.y;
  const int orig = blockIdx.y * gx + blockIdx.x;
  const int qq = nwg >> 3, rm = nwg & 7;
  const int xcd = orig & 7, sidx = orig >> 3;
  const int wg = (xcd < rm ? xcd * (qq + 1) : rm * (qq + 1) + (xcd - rm) * qq) + sidx;
  const int bn0 = (wg % gx) * 128;
  const int bm0 = (wg / gx) * 128;

  // --- fused-secondary selection (uniform per block).
  const bool isH = (MODE == 2) && ga.Wh && (bn0 >= ga.Nintmain);
  const bf16* Wp1 = isH ? ga.Wh : ga.W1;
  const bf16* Wp2 = isH ? ga.Wh : ga.W2;
  const int ldW = isH ? ga.ldWh : ga.ldW;
  const int Wrows = isH ? ga.Wrowsh : ga.Wrows;
  const int bn0L = isH ? bn0 - ga.Nintmain : bn0;
  const int nt1 = (isH ? ga.Kh : ga.K1) >> 6;
  const int nt = (isH ? ga.Kh : ga.Ktot) >> 6;

  // --- staging precompute (swizzle: phys 16B-slot = logical ^ (row&7)).
  const int srow = tid >> 3;
  const int scol = (((tid & 7) ^ (srow & 7)) << 3);  // element offset within row
  const bf16* zp = ga.zpage + tid * 8;
  int offA[4], offB[4];
  bool okA[4], okB[4];
#pragma unroll
  for (int r = 0; r < 4; r++) {
    const int ra = bm0 + r * 32 + srow;
    const int rb = bn0L + r * 32 + srow;
    okA[r] = ra < ga.Arows;
    okB[r] = rb < Wrows;
    offA[r] = ra * ga.ldA + scol;
    offB[r] = rb * ldW + scol;
  }

  auto stage = [&](int t, int p) {
    const int seg = t >= nt1;
    const int koff = (t - (seg ? nt1 : 0)) << 6;
    const bf16* As = seg ? ga.A2 : ga.A1;
    const bf16* Ws = seg ? Wp2 : Wp1;
    bf16* dA = &sA[p][tid * 8];
    bf16* dB = &sB[p][tid * 8];
#pragma unroll
    for (int r = 0; r < 4; r++)
      async_copy16(okA[r] ? As + offA[r] + koff : zp, dA + r * 2048);
#pragma unroll
    for (int r = 0; r < 4; r++)
      async_copy16(okB[r] ? Ws + offB[r] + koff : zp, dB + r * 2048);
  };

  // --- fragment-read precompute.
  const int sl = lane >> 4;
  const int rAb = wm * 64 + (lane & 15);
  const int rBb = wn * 64 + (lane & 15);
  const int a7 = rAb & 7, b7 = rBb & 7;

  f32x4 acc[4][4] = {};

  // --- prologue: stage tiles 0,1; wait tile0 (8 of tile1 stay in flight).
  stage(0, 0);
  stage(1, 1);
  asm volatile("s_waitcnt vmcnt(8)" ::: "memory");
  __builtin_amdgcn_s_barrier();
  asm volatile("" ::: "memory");

  for (int t = 0; t < nt; ++t) {
    const int p = t & 1;
    const bf16* pA = &sA[p][0];
    const bf16* pB = &sB[p][0];
    bf16x8 af[4][2], bv[4][2];
#pragma unroll
    for (int mi = 0; mi < 4; mi++)
#pragma unroll
      for (int kk = 0; kk < 2; kk++)
        af[mi][kk] = *(const bf16x8*)((const char*)pA + (rAb + mi * 16) * 128 +
                                      ((((kk << 2) + sl) ^ a7) << 4));
#pragma unroll
    for (int ni = 0; ni < 4; ni++)
#pragma unroll
      for (int kk = 0; kk < 2; kk++)
        bv[ni][kk] = *(const bf16x8*)((const char*)pB + (rBb + ni * 16) * 128 +
                                      ((((kk << 2) + sl) ^ b7) << 4));
    if (t + 2 < nt) {
      asm volatile("s_waitcnt lgkmcnt(0)" ::: "memory");
      __builtin_amdgcn_s_barrier();
      asm volatile("" ::: "memory");
      stage(t + 2, p);  // issue early: HBM latency hides under MFMA below
    }
    __builtin_amdgcn_s_setprio(1);
#pragma unroll
    for (int mi = 0; mi < 4; mi++)
#pragma unroll
      for (int ni = 0; ni < 4; ni++)
#pragma unroll
        for (int kk = 0; kk < 2; kk++)
          acc[mi][ni] =
              __builtin_amdgcn_mfma_f32_16x16x32_bf16(af[mi][kk], bv[ni][kk], acc[mi][ni], 0, 0, 0);
    __builtin_amdgcn_s_setprio(0);
    if (t + 1 < nt) {
      if (t + 2 < nt) asm volatile("s_waitcnt vmcnt(8)" ::: "memory");
      else            asm volatile("s_waitcnt vmcnt(0)" ::: "memory");
      __builtin_amdgcn_s_barrier();
      asm volatile("" ::: "memory");
    }
  }

  if constexpr (MODE == 0) {
    const int Nv = ga.Nvalid;
#pragma unroll
    for (int mi = 0; mi < 4; mi++) {
      const int rb = bm0 + wm * 64 + mi * 16 + ((lane >> 4) << 2);
#pragma unroll
      for (int ni = 0; ni < 4; ni++) {
        const int c = bn0 + wn * 64 + ni * 16 + (lane & 15);
#pragma unroll
        for (int i = 0; i < 4; i++) {
          const int r = rb + i;
          if (r < ga.Nrows && c < Nv) ga.outB[(size_t)r * ga.ldC + c] = (bf16)acc[mi][ni][i];
        }
      }
    }
  } else if constexpr (MODE == 2) {
    if (isH) {
#pragma unroll
      for (int mi = 0; mi < 4; mi++) {
        const int rb = bm0 + wm * 64 + mi * 16 + ((lane >> 4) << 2);
#pragma unroll
        for (int ni = 0; ni < 4; ni++) {
          const int c = bn0L + wn * 64 + ni * 16 + (lane & 15);
#pragma unroll
          for (int i = 0; i < 4; i++) {
            const int r = rb + i;
            if (r < ga.Nrows && c < ga.ldC) ga.outB[(size_t)r * ga.ldC + c] = (bf16)acc[mi][ni][i];
          }
        }
      }
    } else {
      const int Dr = ga.Nvalid;  // logical width
      const int Lb = ((bn0 + wn * 64) >> 1) + (lane & 15);
#pragma unroll
      for (int mi = 0; mi < 4; mi++) {
        const int rb = bm0 + wm * 64 + mi * 16 + ((lane >> 4) << 2);
#pragma unroll
        for (int p = 0; p < 2; p++) {
          const int L = Lb + p * 16;
          const float mv = ga.mrow[L];
#pragma unroll
          for (int i = 0; i < 4; i++) {
            const int r = rb + i;
            if (r >= ga.Nrows) continue;
            const size_t idx = (size_t)r * Dr + L;
            float vg = acc[mi][2 * p][i];
            float vb = acc[mi][2 * p + 1][i];
            float gamma = (vg > 0.f ? vg : 0.2f * vg) + 1.0f;
            float beta = vb > 0.f ? vb : 0.2f * vb;
            float ft = ga.Xf ? ga.Xf[idx] : (float)ga.Xh[idx];
            float o = ft + gamma * mv + beta - (float)ga.nbm[idx];
            ga.outG[idx] = o;
            ga.outB2[idx] = (bf16)o;
          }
        }
      }
    }
  } else if constexpr (MODE == 3) {
    const int Nv = ga.Nvalid;
#pragma unroll
    for (int mi = 0; mi < 4; mi++) {
      const int rb = bm0 + wm * 64 + mi * 16 + ((lane >> 4) << 2);
#pragma unroll
      for (int ni = 0; ni < 4; ni++) {
        const int c = bn0 + wn * 64 + ni * 16 + (lane & 15);
#pragma unroll
        for (int i = 0; i < 4; i++) {
          const int r = rb + i;
          if (r >= ga.Nrows || c >= Nv) continue;
          const size_t idx = (size_t)r * ga.ldC + c;
          float dv = ga.dinv[r];
          float hs = (float)ga.hself[(size_t)r * ga.hld + c];
          float hv = (ga.agg[idx] + dv * dv * hs + ga.bias[c] + acc[mi][ni][i]) * ga.rnb[r];
          if (ga.elu) hv = hv > 0.f ? hv : expm1f(hv);
          ga.outB[idx] = (bf16)hv;
        }
      }
    }
  } else {  // MODE 4: GCN combine + fused log_softmax (Nvalid == 64, wn==0 waves only)
    if (wn == 0) {
#pragma unroll
      for (int mi = 0; mi < 4; mi++) {
        const int rb = bm0 + wm * 64 + mi * 16 + ((lane >> 4) << 2);
#pragma unroll
        for (int i = 0; i < 4; i++) {
          const int r = rb + i;
          const bool ok = r < ga.Nrows;  // uniform within the 16-lane shuffle group
          float dv = ok ? ga.dinv[r] : 0.f;
          float rn = ok ? ga.rnb[r] : 1.f;
          float hv[4];
#pragma unroll
          for (int ni = 0; ni < 4; ni++) {
            const int c = ni * 16 + (lane & 15);
            float hs = ok ? (float)ga.hself[(size_t)r * ga.hld + c] : 0.f;
            float ag = ok ? ga.agg[(size_t)r * 64 + c] : 0.f;
            hv[ni] = ok ? (ag + dv * dv * hs + ga.bias[c] + acc[mi][ni][i]) * rn : 0.f;
          }
          float mx = fmaxf(fmaxf(hv[0], hv[1]), fmaxf(hv[2], hv[3]));
          mx = fmaxf(mx, __shfl_xor(mx, 1));
          mx = fmaxf(mx, __shfl_xor(mx, 2));
          mx = fmaxf(mx, __shfl_xor(mx, 4));
          mx = fmaxf(mx, __shfl_xor(mx, 8));
          float s = expf(hv[0] - mx) + expf(hv[1] - mx) + expf(hv[2] - mx) + expf(hv[3] - mx);
          s += __shfl_xor(s, 1);
          s += __shfl_xor(s, 2);
          s += __shfl_xor(s, 4);
          s += __shfl_xor(s, 8);
          float ls = logf(s);
          if (ok) {
#pragma unroll
            for (int ni = 0; ni < 4; ni++) {
              const int c = ni * 16 + (lane & 15);
              ga.outF[(size_t)r * 64 + c] = hv[ni];
              ga.outF2[(size_t)r * 64 + c] = hv[ni] - mx - ls;
            }
          }
        }
      }
    }
  }
}

// ---------------------------------------------------------------------------
// prep_all: one dispatch replacing cvt_f2b x3, build_rel_w x2, and the three
// memsets (icr/icc/zpage). Region-dispatched by blockIdx.
// ---------------------------------------------------------------------------
#define PREP_NB0 10000
#define PREP_NB1 10128
#define PREP_NB2 10144
#define PREP_NB3 11168
#define PREP_NB4 11424
#define PREP_NB5 11589

__device__ __forceinline__ void cvt4(const float* __restrict__ src, bf16* __restrict__ dst,
                                     int i) {
  float4 v = *(const float4*)(src + i);
  union { bf16 b[4]; uint2 u; } o;
  o.b[0] = (bf16)v.x; o.b[1] = (bf16)v.y; o.b[2] = (bf16)v.z; o.b[3] = (bf16)v.w;
  *(uint2*)(dst + i) = o.u;
}

__device__ __forceinline__ void relw4(const float* __restrict__ g1, const float* __restrict__ g2,
                                      const float* __restrict__ b1, const float* __restrict__ b2,
                                      bf16* __restrict__ dst, int D, int idx) {
  int R = idx / (2 * D), C = idx % (2 * D);
  int q = R >> 5, s = R & 31;
  int sr = q * 16 + (s & 15);
  const float* src = (s < 16) ? ((C < D) ? g1 : g2) : ((C < D) ? b1 : b2);
  int cc = (C < D) ? C : C - D;
  float4 v = *(const float4*)(src + (size_t)sr * D + cc);
  union { bf16 b[4]; uint2 u; } o;
  o.b[0] = (bf16)v.x; o.b[1] = (bf16)v.y; o.b[2] = (bf16)v.z; o.b[3] = (bf16)v.w;
  *(uint2*)(dst + (size_t)R * 2 * D + C) = o.u;
}

__global__ __launch_bounds__(256) void prep_all(
    const float* __restrict__ x, const float* __restrict__ gc1w, const float* __restrict__ gc2w,
    const float* __restrict__ r1g1, const float* __restrict__ r1g2,
    const float* __restrict__ r1b1, const float* __restrict__ r1b2,
    const float* __restrict__ r2g1, const float* __restrict__ r2g2,
    const float* __restrict__ r2b1, const float* __restrict__ r2b2,
    bf16* __restrict__ xb, bf16* __restrict__ wgc1, bf16* __restrict__ wgc2,
    bf16* __restrict__ Wrel1, bf16* __restrict__ Wrel2,
    int* __restrict__ icr, int* __restrict__ icc, int* __restrict__ zpage) {
  const int b = blockIdx.x;
  const int tid = threadIdx.x;
  if (b < PREP_NB0) {
    cvt4(x, xb, (b * 256 + tid) * 4);
  } else if (b < PREP_NB1) {
    cvt4(gc1w, wgc1, ((b - PREP_NB0) * 256 + tid) * 4);
  } else if (b < PREP_NB2) {
    cvt4(gc2w, wgc2, ((b - PREP_NB1) * 256 + tid) * 4);
  } else if (b < PREP_NB3) {
    relw4(r1g1, r1g2, r1b1, r1b2, Wrel1, 512, ((b - PREP_NB2) * 256 + tid) * 4);
  } else if (b < PREP_NB4) {
    relw4(r2g1, r2g2, r2b1, r2b2, Wrel2, 256, ((b - PREP_NB3) * 256 + tid) * 4);
  } else {
    int i = (b - PREP_NB4) * 256 + tid;
    if (i < NNODE) icr[i] = 0;
    else if (i < 2 * NNODE) icc[i - NNODE] = 0;
    else if (i < 2 * NNODE + 2048) zpage[i - 2 * NNODE] = 0;
  }
}

// ---------------------------------------------------------------------------
// CSR build
// ---------------------------------------------------------------------------
__global__ void count_int(const int* __restrict__ ei, int* cr, int* cc, int E) {
  int e = blockIdx.x * 256 + threadIdx.x;
  if (e < E) {
    atomicAdd(&cr[ei[e]], 1);
    atomicAdd(&cc[ei[E + e]], 1);
  }
}

// scan + folded finalize (nbscale/rnb/dinv from the completed counts)
__global__ void scan_excl2(const int* __restrict__ cr, const int* __restrict__ cc,
                           int* __restrict__ rptr, int* __restrict__ cptr,
                           int* __restrict__ curr, int* __restrict__ curc,
                           float* __restrict__ nbscale, float* __restrict__ rnb,
                           float* __restrict__ dinv, int n) {
  int t = threadIdx.x;
  {
    int b0 = blockIdx.x * (n / 2);
    for (int j = b0 + t; j < b0 + n / 2; j += 256) {
      float a = (float)cr[j];
      nbscale[j] = 1.0f / fmaxf(a, 1.0f);
      rnb[j] = 1.0f / (a + 1.0f);
      dinv[j] = rsqrtf((float)cc[j] + 1.0f);
    }
  }
  const int* cnt = blockIdx.x ? cc : cr;
  int* ptr = blockIdx.x ? cptr : rptr;
  int* cur = blockIdx.x ? curc : curr;
  __shared__ int part[256];
  int chunk = (n + 255) / 256;
  int base = t * chunk;
  int s = 0;
  for (int i = 0; i < chunk; i++) {
    int j = base + i;
    if (j < n) s += cnt[j];
  }
  part[t] = s;
  __syncthreads();
  if (t == 0) {
    int r = 0;
    for (int i = 0; i < 256; i++) { int v = part[i]; part[i] = r; r += v; }
    ptr[n] = r;
  }
  __syncthreads();
  int run = part[t];
  for (int i = 0; i < chunk; i++) {
    int j = base + i;
    if (j < n) {
      ptr[j] = run;
      cur[j] = run;
      run += cnt[j];
    }
  }
}

__global__ void csr_fill(const int* __restrict__ ei, int* cur_r, int* cur_c,
                         int* __restrict__ adj_r, int* __restrict__ adj_c, int E) {
  int e = blockIdx.x * 256 + threadIdx.x;
  if (e >= E) return;
  int row = ei[e], col = ei[E + e];
  int p = atomicAdd(&cur_r[row], 1);
  adj_r[p] = col;
  int q = atomicAdd(&cur_c[col], 1);
  adj_c[q] = row;
}

// ---------------------------------------------------------------------------
// Gather SpMM (no atomics): one 64-lane wave per destination node.
// Edge loops unrolled 8-deep for memory-level parallelism.
// ---------------------------------------------------------------------------
__global__ void spmm_nb1(const int* __restrict__ rowptr, const int* __restrict__ adj,
                         const bf16* __restrict__ x, const float* __restrict__ nbscale,
                         bf16* __restrict__ nbp, int n) {
  int r = blockIdx.x * 4 + (threadIdx.x >> 6);
  if (r >= n) return;
  int lane = threadIdx.x & 63;
  int e0 = rowptr[r], e1 = rowptr[r + 1];
  float a[8] = {0.f, 0.f, 0.f, 0.f, 0.f, 0.f, 0.f, 0.f};
  int e = e0;
  for (; e + 8 <= e1; e += 8) {
    union { uint4 u; bf16 b[8]; } v[8];
    int ix[8];
#pragma unroll
    for (int k = 0; k < 8; k++) ix[k] = adj[e + k];
#pragma unroll
    for (int k = 0; k < 8; k++) v[k].u = *(const uint4*)(x + (size_t)ix[k] * NFEATD + lane * 8);
#pragma unroll
    for (int j = 0; j < 8; j++) {
      float t = 0.f;
#pragma unroll
      for (int k = 0; k < 8; k++) t += (float)v[k].b[j];
      a[j] += t;
    }
  }
  for (; e + 4 <= e1; e += 4) {
    int i0 = adj[e], i1 = adj[e + 1], i2 = adj[e + 2], i3 = adj[e + 3];
    union { uint4 u; bf16 b[8]; } v0, v1, v2, v3;
    v0.u = *(const uint4*)(x + (size_t)i0 * NFEATD + lane * 8);
    v1.u = *(const uint4*)(x + (size_t)i1 * NFEATD + lane * 8);
    v2.u = *(const uint4*)(x + (size_t)i2 * NFEATD + lane * 8);
    v3.u = *(const uint4*)(x + (size_t)i3 * NFEATD + lane * 8);
#pragma unroll
    for (int j = 0; j < 8; j++)
      a[j] += (float)v0.b[j] + (float)v1.b[j] + (float)v2.b[j] + (float)v3.b[j];
  }
  for (; e < e1; e++) {
    union { uint4 u; bf16 b[8]; } v;
    v.u = *(const uint4*)(x + (size_t)adj[e] * NFEATD + lane * 8);
#pragma unroll
    for (int j = 0; j < 8; j++) a[j] += (float)v.b[j];
  }
  float s = nbscale[r];
  union { bf16 b[8]; uint4 u; } o;
#pragma unroll
  for (int j = 0; j < 8; j++) o.b[j] = (bf16)(a[j] * s);
  *(uint4*)(nbp + (size_t)r * NFEATD + lane * 8) = o.u;
}

__global__ void spmm_nb2(const int* __restrict__ rowptr, const int* __restrict__ adj,
                         const bf16* __restrict__ x, const float* __restrict__ nbscale,
                         bf16* __restrict__ nbp, int n) {
  int r = blockIdx.x * 4 + (threadIdx.x >> 6);
  if (r >= n) return;
  int lane = threadIdx.x & 63;
  int e0 = rowptr[r], e1 = rowptr[r + 1];
  float a[4] = {0.f, 0.f, 0.f, 0.f};
  int e = e0;
  for (; e + 8 <= e1; e += 8) {
    union { uint2 u; bf16 b[4]; } v[8];
    int ix[8];
#pragma unroll
    for (int k = 0; k < 8; k++) ix[k] = adj[e + k];
#pragma unroll
    for (int k = 0; k < 8; k++) v[k].u = *(const uint2*)(x + (size_t)ix[k] * NHIDD + lane * 4);
#pragma unroll
    for (int j = 0; j < 4; j++) {
      float t = 0.f;
#pragma unroll
      for (int k = 0; k < 8; k++) t += (float)v[k].b[j];
      a[j] += t;
    }
  }
  for (; e + 4 <= e1; e += 4) {
    int i0 = adj[e], i1 = adj[e + 1], i2 = adj[e + 2], i3 = adj[e + 3];
    union { uint2 u; bf16 b[4]; } v0, v1, v2, v3;
    v0.u = *(const uint2*)(x + (size_t)i0 * NHIDD + lane * 4);
    v1.u = *(const uint2*)(x + (size_t)i1 * NHIDD + lane * 4);
    v2.u = *(const uint2*)(x + (size_t)i2 * NHIDD + lane * 4);
    v3.u = *(const uint2*)(x + (size_t)i3 * NHIDD + lane * 4);
#pragma unroll
    for (int j = 0; j < 4; j++)
      a[j] += (float)v0.b[j] + (float)v1.b[j] + (float)v2.b[j] + (float)v3.b[j];
  }
  for (; e < e1; e++) {
    union { uint2 u; bf16 b[4]; } v;
    v.u = *(const uint2*)(x + (size_t)adj[e] * NHIDD + lane * 4);
#pragma unroll
    for (int j = 0; j < 4; j++) a[j] += (float)v.b[j];
  }
  float s = nbscale[r];
  union { bf16 b[4]; uint2 u; } o;
#pragma unroll
  for (int j = 0; j < 4; j++) o.b[j] = (bf16)(a[j] * s);
  *(uint2*)(nbp + (size_t)r * NHIDD + lane * 4) = o.u;
}

__global__ void spmm_gcn256(const int* __restrict__ colptr, const int* __restrict__ adj,
                            const bf16* __restrict__ h, int hld, const float* __restrict__ dinv,
                            float* __restrict__ agg, int n) {
  int c = blockIdx.x * 4 + (threadIdx.x >> 6);
  if (c >= n) return;
  int lane = threadIdx.x & 63;
  int e0 = colptr[c], e1 = colptr[c + 1];
  float a[4] = {0.f, 0.f, 0.f, 0.f};
  int e = e0;
  for (; e + 4 <= e1; e += 4) {
    int i0 = adj[e], i1 = adj[e + 1], i2 = adj[e + 2], i3 = adj[e + 3];
    float w0 = dinv[i0], w1 = dinv[i1], w2 = dinv[i2], w3 = dinv[i3];
    union { uint2 u; bf16 b[4]; } v0, v1, v2, v3;
    v0.u = *(const uint2*)(h + (size_t)i0 * hld + lane * 4);
    v1.u = *(const uint2*)(h + (size_t)i1 * hld + lane * 4);
    v2.u = *(const uint2*)(h + (size_t)i2 * hld + lane * 4);
    v3.u = *(const uint2*)(h + (size_t)i3 * hld + lane * 4);
#pragma unroll
    for (int j = 0; j < 4; j++)
      a[j] += w0 * (float)v0.b[j] + w1 * (float)v1.b[j] + w2 * (float)v2.b[j] + w3 * (float)v3.b[j];
  }
  for (; e < e1; e++) {
    int rr = adj[e];
    float wv = dinv[rr];
    union { uint2 u; bf16 b[4]; } v;
    v.u = *(const uint2*)(h + (size_t)rr * hld + lane * 4);
#pragma unroll
    for (int j = 0; j < 4; j++) a[j] += wv * (float)v.b[j];
  }
  float wc = dinv[c];
  f32x4 o;
#pragma unroll
  for (int j = 0; j < 4; j++) o[j] = a[j] * wc;
  *(f32x4*)(agg + (size_t)c * NHIDD + lane * 4) = o;
}

__global__ void spmm_gcn64(const int* __restrict__ colptr, const int* __restrict__ adj,
                           const bf16* __restrict__ h, int hld, const float* __restrict__ dinv,
                           float* __restrict__ agg, int n) {
  int c = blockIdx.x * 4 + (threadIdx.x >> 6);
  if (c >= n) return;
  int lane = threadIdx.x & 63;
  int e0 = colptr[c], e1 = colptr[c + 1];
  float a = 0.f;
  int e = e0;
  for (; e + 4 <= e1; e += 4) {
    int i0 = adj[e], i1 = adj[e + 1], i2 = adj[e + 2], i3 = adj[e + 3];
    float h0 = (float)h[(size_t)i0 * hld + lane];
    float h1 = (float)h[(size_t)i1 * hld + lane];
    float h2 = (float)h[(size_t)i2 * hld + lane];
    float h3 = (float)h[(size_t)i3 * hld + lane];
    a += dinv[i0] * h0 + dinv[i1] * h1 + dinv[i2] * h2 + dinv[i3] * h3;
  }
  for (; e < e1; e++) {
    int rr = adj[e];
    a += dinv[rr] * (float)h[(size_t)rr * hld + lane];
  }
  agg[(size_t)c * NCLSD + lane] = a * dinv[c];
}

// ---------------------------------------------------------------------------
extern "C" void kernel_launch(void* const* d_in, const int* in_sizes, int n_in, void* d_out,
                              int out_size, void* d_ws, size_t ws_size, hipStream_t stream) {
  const float* x = (const float*)d_in[0];
  const int* ei = (const int*)d_in[1];
  // d_in[2] = head (always 0 -> tail branch)
  const float* r1g1 = (const float*)d_in[3];
  const float* r1g2 = (const float*)d_in[4];
  const float* r1b1 = (const float*)d_in[5];
  const float* r1b2 = (const float*)d_in[6];
  const float* r1m = (const float*)d_in[7];
  const float* gc1w = (const float*)d_in[8];
  const float* gc1b = (const float*)d_in[9];
  const float* r2g1 = (const float*)d_in[10];
  const float* r2g2 = (const float*)d_in[11];
  const float* r2b1 = (const float*)d_in[12];
  const float* r2b2 = (const float*)d_in[13];
  const float* r2m = (const float*)d_in[14];
  const float* gc2w = (const float*)d_in[15];
  const float* gc2b = (const float*)d_in[16];
  float* out = (float*)d_out;

  char* ws = (char*)d_ws;
  size_t off = 0;
  auto alloc = [&](size_t bytes) -> char* {
    char* p = ws + off;
    off = (off + bytes + 511) & ~(size_t)511;
    return p;
  };
  float* nbscale = (float*)alloc((size_t)NNODE * 4);
  float* rnb = (float*)alloc((size_t)NNODE * 4);
  float* dinv = (float*)alloc((size_t)NNODE * 4);
  int* icr = (int*)alloc((size_t)NNODE * 4);
  int* icc = (int*)alloc((size_t)NNODE * 4);
  int* rptr = (int*)alloc((size_t)(NNODE + 1) * 4);
  int* cptr = (int*)alloc((size_t)(NNODE + 1) * 4);
  int* curr = (int*)alloc((size_t)NNODE * 4);
  int* curc = (int*)alloc((size_t)NNODE * 4);
  int* adjr = (int*)alloc((size_t)NEDGE * 4);
  int* adjc = (int*)alloc((size_t)NEDGE * 4);
  bf16* zpage = (bf16*)alloc(8192);
  bf16* Wrel1 = (bf16*)alloc((size_t)1024 * 1024 * 2);  // interleaved [g;b] layer1
  bf16* Wrel2 = (bf16*)alloc((size_t)512 * 512 * 2);    // interleaved [g;b] layer2
  bf16* wgc1 = (bf16*)alloc((size_t)NHIDD * NFEATD * 2);
  bf16* wgc2 = (bf16*)alloc((size_t)NCLSD * NHIDD * 2);
  bf16* xb = (bf16*)alloc((size_t)NNODE * NFEATD * 2);     // 20.5 MB
  bf16* nbp1 = (bf16*)alloc((size_t)NNODE * NFEATD * 2);   // 20.5 MB
  bf16* out1b = (bf16*)alloc((size_t)NNODE * NFEATD * 2);  // 20.5 MB
  bf16* h1b = (bf16*)alloc((size_t)NNODE * NHIDD * 2);     // 10.2 MB
  float* agg1 = (float*)alloc((size_t)NNODE * NHIDD * 4);  // 20.5 MB
  bf16* x1b = (bf16*)alloc((size_t)NNODE * NHIDD * 2);     // 10.2 MB
  bf16* nb2p = (bf16*)alloc((size_t)NNODE * NHIDD * 2);    // 10.2 MB
  bf16* out2b = (bf16*)alloc((size_t)NNODE * NHIDD * 2);   // 10.2 MB
  bf16* h2b = (bf16*)alloc((size_t)NNODE * NCLSD * 2);     // 2.6 MB
  float* agg2 = (float*)alloc((size_t)NNODE * NCLSD * 4);  // 5.1 MB

  const size_t OUT1OFF = (size_t)2 * NNODE * NCLSD;
  const size_t OUT2OFF = OUT1OFF + (size_t)NNODE * NFEATD;
  float* out1g = out + OUT1OFF;
  float* out2g = out + OUT2OFF;

  const int MB = (NNODE + 127) / 128;  // 157
  const int NW4 = (NNODE + 3) / 4;

  // ---- fused prep: conversions + weight builders + counter/zpage zeroing ----
  prep_all<<<PREP_NB5, 256, 0, stream>>>(x, gc1w, gc2w, r1g1, r1g2, r1b1, r1b2,
                                         r2g1, r2g2, r2b1, r2b2, xb, wgc1, wgc2,
                                         Wrel1, Wrel2, icr, icc, (int*)zpage);

  // ---- CSR build + graph stats ----
  count_int<<<(NEDGE + 255) / 256, 256, 0, stream>>>(ei, icr, icc, NEDGE);
  scan_excl2<<<2, 256, 0, stream>>>(icr, icc, rptr, cptr, curr, curc, nbscale, rnb, dinv, NNODE);
  csr_fill<<<(NEDGE + 255) / 256, 256, 0, stream>>>(ei, curr, curc, adjr, adjc, NEDGE);

  // ---- layer 1 neighbor mean ----
  spmm_nb1<<<NW4, 256, 0, stream>>>(rptr, adjr, xb, nbscale, nbp1, NNODE);

  GemmArgs a;
  auto base = [&](const bf16* A1, const bf16* A2, int ldA, const bf16* W1, const bf16* W2,
                  int ldW, int K1, int Kt, int Nv, int ldC, int Wr) {
    a = GemmArgs{};
    a.A1 = A1; a.A2 = A2; a.W1 = W1; a.W2 = W2; a.zpage = zpage;
    a.ldA = ldA; a.ldW = ldW; a.K1 = K1; a.Ktot = Kt; a.Nvalid = Nv; a.ldC = ldC;
    a.Nrows = NNODE; a.Arows = NNODE; a.Wrows = Wr;
  };

  // ---- fused layer-1: relation GEMM (cols 0..1023) + h1 = xb@gc1^T (cols 1024..1279)
  base(xb, nbp1, NFEATD, Wrel1, Wrel1 + 512, 1024, NFEATD, 2 * NFEATD, NFEATD, NHIDD, 1024);
  a.mrow = r1m; a.Xf = x; a.nbm = nbp1; a.outG = out1g; a.outB2 = out1b;
  a.Wh = wgc1; a.ldWh = NFEATD; a.Wrowsh = NHIDD; a.Kh = NFEATD; a.Nintmain = 1024;
  a.outB = h1b;  // ldC = NHIDD
  gemm_bt<2><<<dim3(10, MB), 256, 0, stream>>>(a);

  // ---- GCN aggregation layer 1 ----
  spmm_gcn256<<<NW4, 256, 0, stream>>>(cptr, adjc, h1b, NHIDD, dinv, agg1, NNODE);

  // ---- x1 = elu((agg1 + dinv^2*h1 + b1 + out1@gc1^T)*rnb) ----
  base(out1b, out1b, NFEATD, wgc1, wgc1, NFEATD, NFEATD, NFEATD, NHIDD, NHIDD, NHIDD);
  a.agg = agg1; a.hself = h1b; a.hld = NHIDD; a.dinv = dinv; a.bias = gc1b; a.rnb = rnb;
  a.elu = 1; a.outB = x1b;
  gemm_bt<3><<<dim3(2, MB), 256, 0, stream>>>(a);

  // ---- layer 2 neighbor mean ----
  spmm_nb2<<<NW4, 256, 0, stream>>>(rptr, adjr, x1b, nbscale, nb2p, NNODE);

  // ---- fused layer-2: relation GEMM (cols 0..511) + h2 = x1b@gc2^T (cols 512..639)
  base(x1b, nb2p, NHIDD, Wrel2, Wrel2 + 256, 512, NHIDD, 2 * NHIDD, NHIDD, NCLSD, 512);
  a.mrow = r2m; a.Xf = nullptr; a.Xh = x1b; a.nbm = nb2p; a.outG = out2g; a.outB2 = out2b;
  a.Wh = wgc2; a.ldWh = NHIDD; a.Wrowsh = NCLSD; a.Kh = NHIDD; a.Nintmain = 512;
  a.outB = h2b;  // ldC = NCLSD
  gemm_bt<2><<<dim3(5, MB), 256, 0, stream>>>(a);

  // ---- GCN aggregation layer 2 ----
  spmm_gcn64<<<NW4, 256, 0, stream>>>(cptr, adjc, h2b, NCLSD, dinv, agg2, NNODE);

  // ---- x2 + log_softmax fused: (agg2 + dinv^2*h2 + b2 + out2@gc2^T)*rnb ----
  base(out2b, out2b, NHIDD, wgc2, wgc2, NHIDD, NHIDD, NHIDD, NCLSD, NCLSD, NCLSD);
  a.agg = agg2; a.hself = h2b; a.hld = NCLSD; a.dinv = dinv; a.bias = gc2b; a.rnb = rnb;
  a.elu = 0; a.outF = out; a.outF2 = out + (size_t)NNODE * NCLSD;
  gemm_bt<4><<<dim3(1, MB), 256, 0, stream>>>(a);
}